// Round 2
// baseline (19879.095 us; speedup 1.0000x reference)
//
#include <hip/hip_runtime.h>
#include <stdint.h>

// ----------------------------------------------------------------------------
// 2-layer LSTM (T=8192, IN=9, H=1024) + Linear(H->1), fp32, single cooperative
// kernel, 256 blocks x 512 threads (1 block/CU guaranteed co-resident).
//
// Decomposition: block b owns hidden units 4b..4b+3 of BOTH layers.
//   waves 0..3  -> layer-0 unit (4b+wv):   gates = w_hh0[rows]·h1(t-1) + x(t)·w_ih0
//   waves 4..7  -> layer-1 unit (4b+wv-4): gates = w_ih1·h1(t) + w_hh1·h2(t-1)
// Wave->SIMD mapping (w%4) pairs one light L0 wave with one heavy L1 wave per
// SIMD -> per-SIMD per-round VALU work is balanced (~384 cy).
//
// Round r (r=0..T): compute L0 step r (r<T) and L1 step r-1 (r>=1) together —
// a 2-stage software pipeline with a single cross-CU hop per round.
//
// Communication: value-carrying mailboxes. pub[slot][unit] is one u64
//   { seq = step+1 (hi32) | fp32 h (lo32) }
// written once per step with a RELAXED agent-scope 8B atomic store (atomicity
// makes the value self-synchronizing: no tags, no fences, no acquire
// invalidates — one LLC trip to publish, one to discover). Ring depth 4:
// all blocks are provably within 1 round of each other (each round reads ALL
// 2048 slots of the previous round), so slot reuse at distance 4 is race-free.
// Workspace poison 0xAA => seq field reads 0xAAAAAAAA != any real seq <= 8193,
// so poison is the "empty" marker and no workspace initialization is needed.
//
// Weights stay in VGPRs for the whole scan (w_hh0 | w_ih1+w_hh1 rows:
// 16 | 32 float4 per thread). Per-step weight HBM traffic: zero.
// ----------------------------------------------------------------------------

#define TSTEPS 8192
#define HDIM   1024
#define BS     512
#define NBLK   256
#define RINGM  3        // ring mask (depth 4)

typedef unsigned long long u64;
typedef unsigned int u32;

__device__ __forceinline__ float sigm(float x)  { return 1.0f / (1.0f + __expf(-x)); }
__device__ __forceinline__ float tanh_(float x) { return 1.0f - 2.0f / (__expf(2.0f * x) + 1.0f); }
__device__ __forceinline__ float dot4(float4 a, float4 b) {
  return a.x * b.x + a.y * b.y + a.z * b.z + a.w * b.w;
}

// Spin until slot's seq field == want; returns the full word (value in lo32).
__device__ __forceinline__ u64 pollslot(const u64* p, u32 want) {
  u64 v = __hip_atomic_load(p, __ATOMIC_RELAXED, __HIP_MEMORY_SCOPE_AGENT);
  while ((u32)(v >> 32) != want) {
    __builtin_amdgcn_s_sleep(1);
    v = __hip_atomic_load(p, __ATOMIC_RELAXED, __HIP_MEMORY_SCOPE_AGENT);
  }
  return v;
}

__device__ __forceinline__ void publish(u64* p, u32 seq, float h) {
  u64 v = ((u64)seq << 32) | (u64)__float_as_uint(h);
  __hip_atomic_store(p, v, __ATOMIC_RELAXED, __HIP_MEMORY_SCOPE_AGENT);
}

__global__ void __launch_bounds__(BS, 2) lstm_fused(
    const float* __restrict__ xin,   // [T][9]
    const float* __restrict__ wih0,  // [4H][9]
    const float* __restrict__ whh0,  // [4H][H]
    const float* __restrict__ bih0, const float* __restrict__ bhh0,
    const float* __restrict__ wih1,  // [4H][H]
    const float* __restrict__ whh1,  // [4H][H]
    const float* __restrict__ bih1, const float* __restrict__ bhh1,
    const float* __restrict__ wlin, const float* __restrict__ blin,
    float* __restrict__ out,
    u64* __restrict__ pub1, u64* __restrict__ pub2)   // [4][HDIM] each
{
  const int b   = blockIdx.x;
  const int tid = threadIdx.x;
  const int wv  = tid >> 6;
  const int ln  = tid & 63;
  const bool isL0 = (wv < 4);
  const int unit = 4 * b + (wv & 3);       // hidden unit this wave owns

  __shared__ __align__(16) float hA[HDIM]; // h1 of the needed step
  __shared__ __align__(16) float hB[HDIM]; // h2 of the needed step
  __shared__ float red8[8];

  // ---- weights -> registers ----------------------------------------------
  // lane ln holds k-chunks k = 4*ln + 256*j (j=0..3) of each gate row.
  float4 wrr[4][4];                         // L0: w_hh0 rows | L1: w_hh1 rows
  {
    const float* WR = isL0 ? whh0 : whh1;
    #pragma unroll
    for (int g = 0; g < 4; ++g)
      #pragma unroll
      for (int j = 0; j < 4; ++j)
        wrr[g][j] = *reinterpret_cast<const float4*>(
            WR + (size_t)(g * HDIM + unit) * HDIM + 4 * ln + 256 * j);
  }
  float4 wii[4][4];                         // L1 only: w_ih1 rows
  if (!isL0) {
    #pragma unroll
    for (int g = 0; g < 4; ++g)
      #pragma unroll
      for (int j = 0; j < 4; ++j)
        wii[g][j] = *reinterpret_cast<const float4*>(
            wih1 + (size_t)(g * HDIM + unit) * HDIM + 4 * ln + 256 * j);
  }
  float wxr[4][9];                          // L0 only: w_ih0 rows
  if (isL0) {
    #pragma unroll
    for (int g = 0; g < 4; ++g)
      #pragma unroll
      for (int k = 0; k < 9; ++k)
        wxr[g][k] = wih0[(size_t)(g * HDIM + unit) * 9 + k];
  }
  float bias[4];
  #pragma unroll
  for (int g = 0; g < 4; ++g)
    bias[g] = isL0 ? (bih0[g * HDIM + unit] + bhh0[g * HDIM + unit])
                   : (bih1[g * HDIM + unit] + bhh1[g * HDIM + unit]);

  float c = 0.0f;                           // cell state (replicated per lane)

  // ======================== round loop ====================================
  for (int r = 0; r <= TSTEPS; ++r) {
    // x(r) for L0 waves — independent of polls, issue early.
    float xr[9];
    if (isL0 && r < TSTEPS) {
      #pragma unroll
      for (int k = 0; k < 9; ++k) xr[k] = xin[r * 9 + k];
    }

    // ---- poll phase: every thread fetches 2 units of each stream --------
    const int i2 = tid * 2;
    if (r >= 1) {                            // need h1[r-1], seq = r
      const u64* s1 = pub1 + (size_t)((r - 1) & RINGM) * HDIM;
      u64 va = pollslot(s1 + i2, (u32)r);
      u64 vb = pollslot(s1 + i2 + 1, (u32)r);
      hA[i2]     = __uint_as_float((u32)va);
      hA[i2 + 1] = __uint_as_float((u32)vb);
    } else {
      hA[i2] = 0.0f; hA[i2 + 1] = 0.0f;
    }
    if (r >= 2) {                            // need h2[r-2], seq = r-1
      const u64* s2 = pub2 + (size_t)((r - 2) & RINGM) * HDIM;
      u64 va = pollslot(s2 + i2, (u32)(r - 1));
      u64 vb = pollslot(s2 + i2 + 1, (u32)(r - 1));
      hB[i2]     = __uint_as_float((u32)va);
      hB[i2 + 1] = __uint_as_float((u32)vb);
    } else {
      hB[i2] = 0.0f; hB[i2 + 1] = 0.0f;
    }
    __syncthreads();                         // LDS staged for all waves

    // ---- compute phase --------------------------------------------------
    if (isL0) {
      if (r < TSTEPS) {
        float a0 = 0, a1 = 0, a2 = 0, a3 = 0;
        #pragma unroll
        for (int j = 0; j < 4; ++j) {
          float4 h4 = reinterpret_cast<const float4*>(hA)[ln + (j << 6)];
          a0 += dot4(wrr[0][j], h4); a1 += dot4(wrr[1][j], h4);
          a2 += dot4(wrr[2][j], h4); a3 += dot4(wrr[3][j], h4);
        }
        #pragma unroll
        for (int d = 1; d < 64; d <<= 1) {
          a0 += __shfl_xor(a0, d); a1 += __shfl_xor(a1, d);
          a2 += __shfl_xor(a2, d); a3 += __shfl_xor(a3, d);
        }
        float g0 = a0 + bias[0], g1 = a1 + bias[1];
        float g2 = a2 + bias[2], g3 = a3 + bias[3];
        #pragma unroll
        for (int k = 0; k < 9; ++k) {
          g0 += wxr[0][k] * xr[k]; g1 += wxr[1][k] * xr[k];
          g2 += wxr[2][k] * xr[k]; g3 += wxr[3][k] * xr[k];
        }
        float gi = sigm(g0), gf = sigm(g1), gg = tanh_(g2), go = sigm(g3);
        c = gf * c + gi * gg;
        float h = go * tanh_(c);
        if (ln == 0)
          publish(pub1 + (size_t)(r & RINGM) * HDIM + unit, (u32)(r + 1), h);
      }
    } else {
      if (r >= 1) {                          // L1 step s = r-1
        float a0 = 0, a1 = 0, a2 = 0, a3 = 0;
        #pragma unroll
        for (int j = 0; j < 4; ++j) {
          float4 ha = reinterpret_cast<const float4*>(hA)[ln + (j << 6)];
          float4 hb = reinterpret_cast<const float4*>(hB)[ln + (j << 6)];
          a0 += dot4(wii[0][j], ha) + dot4(wrr[0][j], hb);
          a1 += dot4(wii[1][j], ha) + dot4(wrr[1][j], hb);
          a2 += dot4(wii[2][j], ha) + dot4(wrr[2][j], hb);
          a3 += dot4(wii[3][j], ha) + dot4(wrr[3][j], hb);
        }
        #pragma unroll
        for (int d = 1; d < 64; d <<= 1) {
          a0 += __shfl_xor(a0, d); a1 += __shfl_xor(a1, d);
          a2 += __shfl_xor(a2, d); a3 += __shfl_xor(a3, d);
        }
        float g0 = a0 + bias[0], g1 = a1 + bias[1];
        float g2 = a2 + bias[2], g3 = a3 + bias[3];
        float gi = sigm(g0), gf = sigm(g1), gg = tanh_(g2), go = sigm(g3);
        c = gf * c + gi * gg;
        float h = go * tanh_(c);
        if (ln == 0)
          publish(pub2 + (size_t)((r - 1) & RINGM) * HDIM + unit, (u32)r, h);
      }
    }
    __syncthreads();                         // hA/hB reads done before re-stage
  }

  // ---- final Linear(h2[T-1]) by block 0 ----------------------------------
  if (b == 0) {
    const u64* s2 = pub2 + (size_t)((TSTEPS - 1) & RINGM) * HDIM;
    const int i2 = tid * 2;
    u64 va = pollslot(s2 + i2, (u32)TSTEPS);
    u64 vb = pollslot(s2 + i2 + 1, (u32)TSTEPS);
    float p = __uint_as_float((u32)va) * wlin[i2]
            + __uint_as_float((u32)vb) * wlin[i2 + 1];
    #pragma unroll
    for (int d = 1; d < 64; d <<= 1) p += __shfl_xor(p, d);
    if (ln == 0) red8[wv] = p;
    __syncthreads();
    if (tid == 0) {
      float s = blin[0];
      #pragma unroll
      for (int w = 0; w < 8; ++w) s += red8[w];
      out[0] = s;
    }
  }
}

extern "C" void kernel_launch(void* const* d_in, const int* in_sizes, int n_in,
                              void* d_out, int out_size, void* d_ws, size_t ws_size,
                              hipStream_t stream)
{
  const float* xin  = (const float*)d_in[0];
  const float* wih0 = (const float*)d_in[1];
  const float* whh0 = (const float*)d_in[2];
  const float* bih0 = (const float*)d_in[3];
  const float* bhh0 = (const float*)d_in[4];
  const float* wih1 = (const float*)d_in[5];
  const float* whh1 = (const float*)d_in[6];
  const float* bih1 = (const float*)d_in[7];
  const float* bhh1 = (const float*)d_in[8];
  const float* wlin = (const float*)d_in[9];
  const float* blin = (const float*)d_in[10];
  float* out = (float*)d_out;

  // Ring mailboxes in ws: pub1[4][1024] u64, pub2[4][1024] u64 = 64 KB total.
  // 0xAA poison acts as the "empty" marker (seq field 0xAAAAAAAA never valid).
  u64* pub1 = (u64*)d_ws;
  u64* pub2 = pub1 + 4 * HDIM;

  void* args[] = { &xin, &wih0, &whh0, &bih0, &bhh0,
                   &wih1, &whh1, &bih1, &bhh1, &wlin, &blin,
                   &out, &pub1, &pub2 };
  hipLaunchCooperativeKernel(reinterpret_cast<void*>(&lstm_fused),
                             dim3(NBLK), dim3(BS), args, 0, stream);
}